// Round 1
// baseline (49290.759 us; speedup 1.0000x reference)
//
#include <hip/hip_runtime.h>
#include <hip/hip_bf16.h>

// ---------------------------------------------------------------------------
// Bidirectional 2-layer GRU encoder, B=64, S=512, D=H=512.
//   1) convert_kernel: all 6 weight tensors fp32 -> bf16 (once per call)
//   2) xproj_kernel(layer): X @ Wx{z,r,h}^T + b  as MFMA GEMM.
//        layer0: A = embedding gather (tokens->table, PAD row = 0)
//        layer1: A = layer-0 hidden outputs (bf16)
//        gates z,r stored bf16; gate h stored fp32 (accuracy).
//   3) recur_kernel(layer): persistent, 32 WGs = 2 dirs x 16 col-groups.
//        Each WG owns 32 output columns; Whz/Whr/Whh rows live in VGPRs.
//        Per step: P1 (z,r + publish r*h hi/lo bf16) -> flag -> P2 (h~ via
//        3 MFMAs: rh_hi*W_hi + rh_lo*W_hi + rh_hi*W_lo(LDS)) -> publish h
//        (fp32 + bf16 mirror) -> flag.  Flags are monotone step counters,
//        device-scope release/acquire; h double-buffered.
// ---------------------------------------------------------------------------

typedef short bf16x8 __attribute__((ext_vector_type(8)));
typedef float f32x4  __attribute__((ext_vector_type(4)));
typedef unsigned short u16x8 __attribute__((ext_vector_type(8)));

#define SBH 16777216ull   // S*B*H = 512*64*512

__device__ __forceinline__ unsigned short f2b(float f){
  __hip_bfloat16 h = __float2bfloat16(f);
  unsigned short u; __builtin_memcpy(&u, &h, 2); return u;
}
__device__ __forceinline__ float b2f(unsigned short u){
  __hip_bfloat16 h; __builtin_memcpy(&h, &u, 2); return __bfloat162float(h);
}

// ---------------- workspace layout (bytes) ----------------
#define OFF_HB32   0ull          // 2 dir * 2 slot * 64*512 f32      = 524288
#define OFF_HB16   524288ull     // same, bf16                       = 262144
#define OFF_RHHI   786432ull     // 2 dir * 64*512 bf16              = 131072
#define OFF_RHLO   917504ull     //                                  = 131072
#define OFF_FLAGS  1048576ull    // 256 ints                         = 1024
#define CTRL_BYTES 1049600ull
#define OFF_XPZR   2097152ull    // 4 * SBH bf16 (d x {z,r})         = 134217728
#define OFF_XPH    136314880ull  // 2 * SBH f32  (d)                 = 134217728
#define OFF_H0     270532608ull  // 2 * SBH bf16                     = 67108864
#define OFF_WBF    337641472ull  // 6 * 4 * 512*512 bf16             = 12582912
#define WS_TOTAL   350224384ull

__global__ void sentinel_kernel(float* out){ out[0] = 12345.0f; }

// ---------------- fp32 -> bf16 weight conversion ----------------
__global__ __launch_bounds__(256) void convert_kernel(
    const float* __restrict__ Wxz, const float* __restrict__ Wxr, const float* __restrict__ Wxh,
    const float* __restrict__ Whz, const float* __restrict__ Whr, const float* __restrict__ Whh,
    unsigned short* __restrict__ wbf)
{
  const int tn = blockIdx.y;
  const float* src = (tn==0)?Wxz:(tn==1)?Wxr:(tn==2)?Wxh:(tn==3)?Whz:(tn==4)?Whr:Whh;
  const size_t base = (size_t)tn * 1048576ull;
  const size_t i = ((size_t)blockIdx.x * 256 + threadIdx.x) * 4;
  float4 v = *(const float4*)(src + i);
  ushort4 o;
  o.x = f2b(v.x); o.y = f2b(v.y); o.z = f2b(v.z); o.w = f2b(v.w);
  *(ushort4*)(wbf + base + i) = o;
}

// ---------------- x-projection GEMM ----------------
// grid (256, 8, 6): m-tile 128 (M=32768), n-tile 64 (N=512), z = d*3+gate
__global__ __launch_bounds__(256) void xproj_kernel(
    const int layer,
    const int* __restrict__ tokens, const float* __restrict__ table,
    const unsigned short* __restrict__ h0buf, const unsigned short* __restrict__ wbf,
    const float* __restrict__ bxz, const float* __restrict__ bxr, const float* __restrict__ bxh,
    unsigned short* __restrict__ xpzr, float* __restrict__ xph)
{
  const int d = blockIdx.z / 3, gate = blockIdx.z % 3;
  const int m0 = blockIdx.x * 128, j0 = blockIdx.y * 64;
  const int tid = threadIdx.x;
  const int wv = tid >> 6, lane = tid & 63, l15 = lane & 15, l4 = lane >> 4;

  __shared__ unsigned short Ast[128][40];   // 128 rows x 32 k, pad 40 (2-way ok)

  const unsigned short* wsrc = wbf + ((size_t)(gate*4 + d*2 + layer)) * 262144ull;
  const float* bias = ((gate==0) ? bxz : (gate==1) ? bxr : bxh) + (d*2 + layer)*512;
  const unsigned short* h0d = h0buf + (size_t)d * SBH;

  // staging assignment: thread -> (row, 16-wide k chunk)
  const int srow = tid >> 1;
  const int skc  = (tid & 1) * 16;
  const int sm   = m0 + srow;
  int stok = 0;
  if (layer == 0){
    int ss = sm >> 6, sb = sm & 63;
    stok = tokens[sb*512 + ss];
  }

  f32x4 acc[2][4];
  #pragma unroll
  for (int a = 0; a < 2; ++a)
    #pragma unroll
    for (int n = 0; n < 4; ++n) acc[a][n] = (f32x4){0.f,0.f,0.f,0.f};

  for (int k0 = 0; k0 < 512; k0 += 32){
    if (layer == 0){
      u16x8 u0 = {0,0,0,0,0,0,0,0}, u1 = {0,0,0,0,0,0,0,0};
      if (stok != 0){
        const float* src = table + (size_t)stok*512 + k0 + skc;
        float4 f0 = *(const float4*)(src);
        float4 f1 = *(const float4*)(src + 4);
        float4 f2 = *(const float4*)(src + 8);
        float4 f3 = *(const float4*)(src + 12);
        u0[0]=f2b(f0.x); u0[1]=f2b(f0.y); u0[2]=f2b(f0.z); u0[3]=f2b(f0.w);
        u0[4]=f2b(f1.x); u0[5]=f2b(f1.y); u0[6]=f2b(f1.z); u0[7]=f2b(f1.w);
        u1[0]=f2b(f2.x); u1[1]=f2b(f2.y); u1[2]=f2b(f2.z); u1[3]=f2b(f2.w);
        u1[4]=f2b(f3.x); u1[5]=f2b(f3.y); u1[6]=f2b(f3.z); u1[7]=f2b(f3.w);
      }
      *(u16x8*)&Ast[srow][skc]     = u0;
      *(u16x8*)&Ast[srow][skc + 8] = u1;
    } else {
      const unsigned short* src = h0d + (size_t)sm*512 + k0 + skc;
      *(u16x8*)&Ast[srow][skc]     = *(const u16x8*)(src);
      *(u16x8*)&Ast[srow][skc + 8] = *(const u16x8*)(src + 8);
    }
    __syncthreads();

    bf16x8 wfr[4];
    #pragma unroll
    for (int nb = 0; nb < 4; ++nb)
      wfr[nb] = *(const bf16x8*)(wsrc + (size_t)(j0 + nb*16 + l15)*512 + k0 + l4*8);
    #pragma unroll
    for (int mb = 0; mb < 2; ++mb){
      bf16x8 af = *(const bf16x8*)&Ast[(wv*2 + mb)*16 + l15][l4*8];
      #pragma unroll
      for (int nb = 0; nb < 4; ++nb)
        acc[mb][nb] = __builtin_amdgcn_mfma_f32_16x16x32_bf16(af, wfr[nb], acc[mb][nb], 0,0,0);
    }
    __syncthreads();
  }

  // epilogue: D row = (lane>>4)*4 + reg, col = lane&15   [verified C/D layout]
  if (gate < 2){
    unsigned short* dst = xpzr + (size_t)(d*2 + gate) * SBH;
    #pragma unroll
    for (int mb = 0; mb < 2; ++mb)
      #pragma unroll
      for (int nb = 0; nb < 4; ++nb){
        const int col = j0 + nb*16 + l15;
        const float bv = bias[col];
        #pragma unroll
        for (int i = 0; i < 4; ++i){
          const int mrow = m0 + (wv*2 + mb)*16 + l4*4 + i;
          dst[(size_t)mrow*512 + col] = f2b(acc[mb][nb][i] + bv);
        }
      }
  } else {
    float* dst = xph + (size_t)d * SBH;
    #pragma unroll
    for (int mb = 0; mb < 2; ++mb)
      #pragma unroll
      for (int nb = 0; nb < 4; ++nb){
        const int col = j0 + nb*16 + l15;
        const float bv = bias[col];
        #pragma unroll
        for (int i = 0; i < 4; ++i){
          const int mrow = m0 + (wv*2 + mb)*16 + l4*4 + i;
          dst[(size_t)mrow*512 + col] = acc[mb][nb][i] + bv;
        }
      }
  }
}

// ---------------- persistent recurrence ----------------
__device__ __forceinline__ bool wait16(int* f, int target, int tid, int& budget){
  if (target > 0){
    for (;;){
      bool ok = true;
      if (tid < 16)
        ok = (__hip_atomic_load(&f[tid], __ATOMIC_RELAXED, __HIP_MEMORY_SCOPE_AGENT) >= target);
      if (__syncthreads_count(!ok) == 0) break;
      if (--budget <= 0) return false;   // deadlock failsafe (uniform)
      __builtin_amdgcn_s_sleep(2);
    }
  }
  __threadfence();   // device-scope acquire: invalidate stale L1/L2 lines
  return true;
}

__global__ __launch_bounds__(256,1) void recur_kernel(
    const int layer,
    const unsigned short* __restrict__ xpzr, const float* __restrict__ xph,
    const unsigned short* __restrict__ wbf, const float* __restrict__ WhhF,
    unsigned short* __restrict__ h0buf, float* __restrict__ out,
    const int* __restrict__ lengths,
    float* __restrict__ hb32, unsigned short* __restrict__ hb16,
    unsigned short* __restrict__ rhhi, unsigned short* __restrict__ rhlo,
    int* __restrict__ flags)
{
  const int d = blockIdx.x >> 4, g = blockIdx.x & 15;
  const int tid = threadIdx.x;
  const int wv = tid >> 6, lane = tid & 63, l15 = lane & 15, l4 = lane >> 4;
  const int colg0 = g * 32;

  __shared__ float zL[64][33];                 // z handoff (P1 waves 0-1 -> P2)
  __shared__ int lenL[64];
  __shared__ unsigned short whhlo[32*520];     // Whh residual (bf16), padded rows

  if (tid < 64) lenL[tid] = lengths[tid];

  // Whh lo-part: lo = Whh_f32 - bf16(Whh_f32)
  {
    const size_t whOff = ((size_t)(d*2 + layer))*262144ull + (size_t)colg0*512;
    for (int e = tid; e < 32*512; e += 256){
      int row = e >> 9, k = e & 511;
      float w = WhhF[whOff + (size_t)row*512 + k];
      whhlo[row*520 + k] = f2b(w - b2f(f2b(w)));
    }
  }

  // --- weight fragments in VGPRs (stationary across all 512 steps) ---
  // P1: wave 0,1 -> z cols [0..15],[16..31]; wave 2,3 -> r cols same.
  const int p1gate = wv >> 1;
  const int jb = colg0 + (wv & 1)*16;
  const unsigned short* w1 = wbf + ((size_t)((3 + p1gate)*4 + d*2 + layer)) * 262144ull;
  bf16x8 wf1[16];
  #pragma unroll
  for (int k0 = 0; k0 < 16; ++k0)
    wf1[k0] = *(const bf16x8*)(w1 + (size_t)(jb + l15)*512 + k0*32 + l4*8);
  // P2: Whh hi (same col half per wave)
  const unsigned short* w2 = wbf + ((size_t)(5*4 + d*2 + layer)) * 262144ull;
  bf16x8 wf2[16];
  #pragma unroll
  for (int k0 = 0; k0 < 16; ++k0)
    wf2[k0] = *(const bf16x8*)(w2 + (size_t)(jb + l15)*512 + k0*32 + l4*8);

  float* hb32d = hb32 + (size_t)d*2*32768;
  unsigned short* hb16d = hb16 + (size_t)d*2*32768;
  unsigned short* rhhd = rhhi + (size_t)d*32768;
  unsigned short* rhld = rhlo + (size_t)d*32768;
  int* fR = flags + d*64;
  int* fH = fR + 32;
  const unsigned short* xpz = xpzr + (size_t)(d*2 + 0)*SBH;
  const unsigned short* xpr = xpzr + (size_t)(d*2 + 1)*SBH;
  const float*          xpd = xph  + (size_t)d*SBH;

  const int myj = colg0 + (wv & 1)*16 + l15;   // elementwise column of this lane
  int budget = 1 << 21;
  __syncthreads();

  for (int t = 0; t < 512; ++t){
    if (!wait16(fH, t, tid, budget)) return;
    const unsigned short* hr16 = hb16d + (t & 1)*32768;
    const float*          hr32 = hb32d + (t & 1)*32768;
    const int idx = (layer == 0 && d == 1) ? (511 - t) : t;
    const size_t xbase = (size_t)idx * 32768;

    // ---- P1: z,r preacts.  A = h (bf16 mirror), B = Wh{z,r} rows ----
    f32x4 acc[4];
    #pragma unroll
    for (int m = 0; m < 4; ++m) acc[m] = (f32x4){0.f,0.f,0.f,0.f};
    #pragma unroll
    for (int k0 = 0; k0 < 16; ++k0){
      #pragma unroll
      for (int m = 0; m < 4; ++m){
        bf16x8 a = *(const bf16x8*)(hr16 + (size_t)(m*16 + l15)*512 + k0*32 + l4*8);
        acc[m] = __builtin_amdgcn_mfma_f32_16x16x32_bf16(a, wf1[k0], acc[m], 0,0,0);
      }
    }
    if (wv < 2){  // z
      #pragma unroll
      for (int m = 0; m < 4; ++m)
        #pragma unroll
        for (int i = 0; i < 4; ++i){
          int b = m*16 + l4*4 + i;
          float pre = acc[m][i] + b2f(xpz[xbase + (size_t)b*512 + myj]);
          zL[b][(wv & 1)*16 + l15] = 1.f/(1.f + __expf(-pre));
        }
    } else {      // r -> publish rh (hi/lo split)
      #pragma unroll
      for (int m = 0; m < 4; ++m)
        #pragma unroll
        for (int i = 0; i < 4; ++i){
          int b = m*16 + l4*4 + i;
          float pre = acc[m][i] + b2f(xpr[xbase + (size_t)b*512 + myj]);
          float r = 1.f/(1.f + __expf(-pre));
          float rhv = r * hr32[b*512 + myj];
          unsigned short hi = f2b(rhv);
          rhhd[b*512 + myj] = hi;
          rhld[b*512 + myj] = f2b(rhv - b2f(hi));
        }
    }
    __syncthreads();
    if (tid == 0){
      __threadfence();
      __hip_atomic_store(&fR[g], t + 1, __ATOMIC_RELEASE, __HIP_MEMORY_SCOPE_AGENT);
    }
    if (!wait16(fR, t + 1, tid, budget)) return;

    // ---- P2: h~ = tanh(xph + rh @ Whh^T), 3-term split MFMA ----
    f32x4 acc2[2];
    acc2[0] = (f32x4){0.f,0.f,0.f,0.f};
    acc2[1] = (f32x4){0.f,0.f,0.f,0.f};
    #pragma unroll
    for (int k0 = 0; k0 < 16; ++k0){
      bf16x8 wlo = *(const bf16x8*)&whhlo[((wv & 1)*16 + l15)*520 + k0*32 + l4*8];
      #pragma unroll
      for (int m = 0; m < 2; ++m){
        int mb = (wv >> 1)*2 + m;
        bf16x8 ahi = *(const bf16x8*)(rhhd + (size_t)(mb*16 + l15)*512 + k0*32 + l4*8);
        bf16x8 alo = *(const bf16x8*)(rhld + (size_t)(mb*16 + l15)*512 + k0*32 + l4*8);
        acc2[m] = __builtin_amdgcn_mfma_f32_16x16x32_bf16(ahi, wf2[k0], acc2[m], 0,0,0);
        acc2[m] = __builtin_amdgcn_mfma_f32_16x16x32_bf16(alo, wf2[k0], acc2[m], 0,0,0);
        acc2[m] = __builtin_amdgcn_mfma_f32_16x16x32_bf16(ahi, wlo,     acc2[m], 0,0,0);
      }
    }
    float* hw32 = hb32d + ((t + 1) & 1)*32768;
    unsigned short* hw16 = hb16d + ((t + 1) & 1)*32768;
    #pragma unroll
    for (int m = 0; m < 2; ++m){
      #pragma unroll
      for (int i = 0; i < 4; ++i){
        int b = ((wv >> 1)*2 + m)*16 + l4*4 + i;
        float pre = acc2[m][i] + xpd[xbase + (size_t)b*512 + myj];
        float e  = __expf(-2.f*fabsf(pre));
        float th = (1.f - e)/(1.f + e);
        th = (pre < 0.f) ? -th : th;
        float z    = zL[b][(wv & 1)*16 + l15];
        float hold = hr32[b*512 + myj];
        bool  msk  = (t < lenL[b]);
        float hn   = msk ? (hold + z*(th - hold)) : hold;
        hw32[b*512 + myj] = hn;
        hw16[b*512 + myj] = f2b(hn);
        if (layer == 0){
          h0buf[(size_t)d*SBH + ((size_t)t*64 + b)*512 + myj] = f2b(hn);
        } else {
          int sout = d ? (511 - t) : t;
          out[((size_t)b*512 + sout)*1024 + (size_t)d*512 + myj] = msk ? hn : 0.f;
        }
      }
    }
    __syncthreads();
    if (tid == 0){
      __threadfence();
      __hip_atomic_store(&fH[g], t + 1, __ATOMIC_RELEASE, __HIP_MEMORY_SCOPE_AGENT);
    }
  }
}

// ---------------- host launcher ----------------
extern "C" void kernel_launch(void* const* d_in, const int* in_sizes, int n_in,
                              void* d_out, int out_size, void* d_ws, size_t ws_size,
                              hipStream_t stream)
{
  const int*   tokens  = (const int*)  d_in[0];
  const int*   lengths = (const int*)  d_in[1];
  const float* table   = (const float*)d_in[2];
  const float* Wxz = (const float*)d_in[3];
  const float* bxz = (const float*)d_in[4];
  const float* Whz = (const float*)d_in[5];
  const float* Wxr = (const float*)d_in[6];
  const float* bxr = (const float*)d_in[7];
  const float* Whr = (const float*)d_in[8];
  const float* Wxh = (const float*)d_in[9];
  const float* bxh = (const float*)d_in[10];
  const float* Whh = (const float*)d_in[11];
  float* out = (float*)d_out;

  char* ws = (char*)d_ws;
  if (ws_size < WS_TOTAL){
    sentinel_kernel<<<1, 1, 0, stream>>>(out);
    return;
  }
  float*          hb32 = (float*)         (ws + OFF_HB32);
  unsigned short* hb16 = (unsigned short*)(ws + OFF_HB16);
  unsigned short* rhhi = (unsigned short*)(ws + OFF_RHHI);
  unsigned short* rhlo = (unsigned short*)(ws + OFF_RHLO);
  int*            flags= (int*)           (ws + OFF_FLAGS);
  unsigned short* xpzr = (unsigned short*)(ws + OFF_XPZR);
  float*          xph  = (float*)         (ws + OFF_XPH);
  unsigned short* h0   = (unsigned short*)(ws + OFF_H0);
  unsigned short* wbf  = (unsigned short*)(ws + OFF_WBF);

  hipMemsetAsync(ws, 0, CTRL_BYTES, stream);
  convert_kernel<<<dim3(1024, 6), 256, 0, stream>>>(Wxz, Wxr, Wxh, Whz, Whr, Whh, wbf);

  // layer 0
  xproj_kernel<<<dim3(256, 8, 6), 256, 0, stream>>>(0, tokens, table, h0, wbf,
                                                    bxz, bxr, bxh, xpzr, xph);
  recur_kernel<<<dim3(32), 256, 0, stream>>>(0, xpzr, xph, wbf, Whh, h0, out,
                                             lengths, hb32, hb16, rhhi, rhlo, flags);
  // layer 1
  hipMemsetAsync(ws, 0, CTRL_BYTES, stream);
  xproj_kernel<<<dim3(256, 8, 6), 256, 0, stream>>>(1, tokens, table, h0, wbf,
                                                    bxz, bxr, bxh, xpzr, xph);
  recur_kernel<<<dim3(32), 256, 0, stream>>>(1, xpzr, xph, wbf, Whh, h0, out,
                                             lengths, hb32, hb16, rhhi, rhlo, flags);
}

// Round 4
// 45861.935 us; speedup vs baseline: 1.0748x; 1.0748x over previous
//
#include <hip/hip_runtime.h>
#include <hip/hip_bf16.h>

// ---------------------------------------------------------------------------
// Bidirectional 2-layer GRU encoder, B=64, S=512, D=H=512.
// R4 = R1 (proven correct, 49.3ms) with ONE change: the acquire fence in
// wait16 is executed by tid0 only + __syncthreads (physically equivalent:
// buffer_inv/wbl2 act on the CU's L1 / XCD's L2, shared by all waves of the
// WG). Cuts full-L2-maintenance ops from 320/step to 128/step.
// Everything else (layout, math, staging, xproj) is byte-identical to R1.
// ---------------------------------------------------------------------------

typedef short bf16x8 __attribute__((ext_vector_type(8)));
typedef float f32x4  __attribute__((ext_vector_type(4)));
typedef unsigned short u16x8 __attribute__((ext_vector_type(8)));

#define SBH 16777216ull   // S*B*H = 512*64*512

__device__ __forceinline__ unsigned short f2b(float f){
  __hip_bfloat16 h = __float2bfloat16(f);
  unsigned short u; __builtin_memcpy(&u, &h, 2); return u;
}
__device__ __forceinline__ float b2f(unsigned short u){
  __hip_bfloat16 h; __builtin_memcpy(&h, &u, 2); return __bfloat162float(h);
}

// ---------------- workspace layout (bytes) ----------------
#define OFF_HB32   0ull          // 2 dir * 2 slot * 64*512 f32      = 524288
#define OFF_HB16   524288ull     // same, bf16                       = 262144
#define OFF_RHHI   786432ull     // 2 dir * 64*512 bf16              = 131072
#define OFF_RHLO   917504ull     //                                  = 131072
#define OFF_FLAGS  1048576ull    // 256 ints                         = 1024
#define CTRL_BYTES 1049600ull
#define OFF_XPZR   2097152ull    // 4 * SBH bf16 (d x {z,r})         = 134217728
#define OFF_XPH    136314880ull  // 2 * SBH f32  (d)                 = 134217728
#define OFF_H0     270532608ull  // 2 * SBH bf16                     = 67108864
#define OFF_WBF    337641472ull  // 6 * 4 * 512*512 bf16             = 12582912
#define WS_TOTAL   350224384ull

__global__ void sentinel_kernel(float* out){ out[0] = 12345.0f; }

// ---------------- fp32 -> bf16 weight conversion ----------------
__global__ __launch_bounds__(256) void convert_kernel(
    const float* __restrict__ Wxz, const float* __restrict__ Wxr, const float* __restrict__ Wxh,
    const float* __restrict__ Whz, const float* __restrict__ Whr, const float* __restrict__ Whh,
    unsigned short* __restrict__ wbf)
{
  const int tn = blockIdx.y;
  const float* src = (tn==0)?Wxz:(tn==1)?Wxr:(tn==2)?Wxh:(tn==3)?Whz:(tn==4)?Whr:Whh;
  const size_t base = (size_t)tn * 1048576ull;
  const size_t i = ((size_t)blockIdx.x * 256 + threadIdx.x) * 4;
  float4 v = *(const float4*)(src + i);
  ushort4 o;
  o.x = f2b(v.x); o.y = f2b(v.y); o.z = f2b(v.z); o.w = f2b(v.w);
  *(ushort4*)(wbf + base + i) = o;
}

// ---------------- x-projection GEMM ----------------
// grid (256, 8, 6): m-tile 128 (M=32768), n-tile 64 (N=512), z = d*3+gate
__global__ __launch_bounds__(256) void xproj_kernel(
    const int layer,
    const int* __restrict__ tokens, const float* __restrict__ table,
    const unsigned short* __restrict__ h0buf, const unsigned short* __restrict__ wbf,
    const float* __restrict__ bxz, const float* __restrict__ bxr, const float* __restrict__ bxh,
    unsigned short* __restrict__ xpzr, float* __restrict__ xph)
{
  const int d = blockIdx.z / 3, gate = blockIdx.z % 3;
  const int m0 = blockIdx.x * 128, j0 = blockIdx.y * 64;
  const int tid = threadIdx.x;
  const int wv = tid >> 6, lane = tid & 63, l15 = lane & 15, l4 = lane >> 4;

  __shared__ unsigned short Ast[128][40];   // 128 rows x 32 k, pad 40 (2-way ok)

  const unsigned short* wsrc = wbf + ((size_t)(gate*4 + d*2 + layer)) * 262144ull;
  const float* bias = ((gate==0) ? bxz : (gate==1) ? bxr : bxh) + (d*2 + layer)*512;
  const unsigned short* h0d = h0buf + (size_t)d * SBH;

  // staging assignment: thread -> (row, 16-wide k chunk)
  const int srow = tid >> 1;
  const int skc  = (tid & 1) * 16;
  const int sm   = m0 + srow;
  int stok = 0;
  if (layer == 0){
    int ss = sm >> 6, sb = sm & 63;
    stok = tokens[sb*512 + ss];
  }

  f32x4 acc[2][4];
  #pragma unroll
  for (int a = 0; a < 2; ++a)
    #pragma unroll
    for (int n = 0; n < 4; ++n) acc[a][n] = (f32x4){0.f,0.f,0.f,0.f};

  for (int k0 = 0; k0 < 512; k0 += 32){
    if (layer == 0){
      u16x8 u0 = {0,0,0,0,0,0,0,0}, u1 = {0,0,0,0,0,0,0,0};
      if (stok != 0){
        const float* src = table + (size_t)stok*512 + k0 + skc;
        float4 f0 = *(const float4*)(src);
        float4 f1 = *(const float4*)(src + 4);
        float4 f2 = *(const float4*)(src + 8);
        float4 f3 = *(const float4*)(src + 12);
        u0[0]=f2b(f0.x); u0[1]=f2b(f0.y); u0[2]=f2b(f0.z); u0[3]=f2b(f0.w);
        u0[4]=f2b(f1.x); u0[5]=f2b(f1.y); u0[6]=f2b(f1.z); u0[7]=f2b(f1.w);
        u1[0]=f2b(f2.x); u1[1]=f2b(f2.y); u1[2]=f2b(f2.z); u1[3]=f2b(f2.w);
        u1[4]=f2b(f3.x); u1[5]=f2b(f3.y); u1[6]=f2b(f3.z); u1[7]=f2b(f3.w);
      }
      *(u16x8*)&Ast[srow][skc]     = u0;
      *(u16x8*)&Ast[srow][skc + 8] = u1;
    } else {
      const unsigned short* src = h0d + (size_t)sm*512 + k0 + skc;
      *(u16x8*)&Ast[srow][skc]     = *(const u16x8*)(src);
      *(u16x8*)&Ast[srow][skc + 8] = *(const u16x8*)(src + 8);
    }
    __syncthreads();

    bf16x8 wfr[4];
    #pragma unroll
    for (int nb = 0; nb < 4; ++nb)
      wfr[nb] = *(const bf16x8*)(wsrc + (size_t)(j0 + nb*16 + l15)*512 + k0 + l4*8);
    #pragma unroll
    for (int mb = 0; mb < 2; ++mb){
      bf16x8 af = *(const bf16x8*)&Ast[(wv*2 + mb)*16 + l15][l4*8];
      #pragma unroll
      for (int nb = 0; nb < 4; ++nb)
        acc[mb][nb] = __builtin_amdgcn_mfma_f32_16x16x32_bf16(af, wfr[nb], acc[mb][nb], 0,0,0);
    }
    __syncthreads();
  }

  // epilogue: D row = (lane>>4)*4 + reg, col = lane&15   [verified C/D layout]
  if (gate < 2){
    unsigned short* dst = xpzr + (size_t)(d*2 + gate) * SBH;
    #pragma unroll
    for (int mb = 0; mb < 2; ++mb)
      #pragma unroll
      for (int nb = 0; nb < 4; ++nb){
        const int col = j0 + nb*16 + l15;
        const float bv = bias[col];
        #pragma unroll
        for (int i = 0; i < 4; ++i){
          const int mrow = m0 + (wv*2 + mb)*16 + l4*4 + i;
          dst[(size_t)mrow*512 + col] = f2b(acc[mb][nb][i] + bv);
        }
      }
  } else {
    float* dst = xph + (size_t)d * SBH;
    #pragma unroll
    for (int mb = 0; mb < 2; ++mb)
      #pragma unroll
      for (int nb = 0; nb < 4; ++nb){
        const int col = j0 + nb*16 + l15;
        const float bv = bias[col];
        #pragma unroll
        for (int i = 0; i < 4; ++i){
          const int mrow = m0 + (wv*2 + mb)*16 + l4*4 + i;
          dst[(size_t)mrow*512 + col] = acc[mb][nb][i] + bv;
        }
      }
  }
}

// ---------------- persistent recurrence ----------------
// R4 change: acquire fence once per WG (tid0) + barrier, not once per thread.
__device__ __forceinline__ bool wait16(int* f, int target, int tid, int& budget){
  if (target > 0){
    for (;;){
      bool ok = true;
      if (tid < 16)
        ok = (__hip_atomic_load(&f[tid], __ATOMIC_RELAXED, __HIP_MEMORY_SCOPE_AGENT) >= target);
      if (__syncthreads_count(!ok) == 0) break;
      if (--budget <= 0) return false;   // deadlock failsafe (uniform)
      __builtin_amdgcn_s_sleep(2);
    }
  }
  if (tid == 0) __threadfence();   // one acquire per WG: inv acts on shared L1/L2
  __syncthreads();                 // others wait for the invalidate
  return true;
}

__global__ __launch_bounds__(256,1) void recur_kernel(
    const int layer,
    const unsigned short* __restrict__ xpzr, const float* __restrict__ xph,
    const unsigned short* __restrict__ wbf, const float* __restrict__ WhhF,
    unsigned short* __restrict__ h0buf, float* __restrict__ out,
    const int* __restrict__ lengths,
    float* __restrict__ hb32, unsigned short* __restrict__ hb16,
    unsigned short* __restrict__ rhhi, unsigned short* __restrict__ rhlo,
    int* __restrict__ flags)
{
  const int d = blockIdx.x >> 4, g = blockIdx.x & 15;
  const int tid = threadIdx.x;
  const int wv = tid >> 6, lane = tid & 63, l15 = lane & 15, l4 = lane >> 4;
  const int colg0 = g * 32;

  __shared__ float zL[64][33];                 // z handoff (P1 waves 0-1 -> P2)
  __shared__ int lenL[64];
  __shared__ unsigned short whhlo[32*520];     // Whh residual (bf16), padded rows

  if (tid < 64) lenL[tid] = lengths[tid];

  // Whh lo-part: lo = Whh_f32 - bf16(Whh_f32)
  {
    const size_t whOff = ((size_t)(d*2 + layer))*262144ull + (size_t)colg0*512;
    for (int e = tid; e < 32*512; e += 256){
      int row = e >> 9, k = e & 511;
      float w = WhhF[whOff + (size_t)row*512 + k];
      whhlo[row*520 + k] = f2b(w - b2f(f2b(w)));
    }
  }

  // --- weight fragments in VGPRs (stationary across all 512 steps) ---
  const int p1gate = wv >> 1;
  const int jb = colg0 + (wv & 1)*16;
  const unsigned short* w1 = wbf + ((size_t)((3 + p1gate)*4 + d*2 + layer)) * 262144ull;
  bf16x8 wf1[16];
  #pragma unroll
  for (int k0 = 0; k0 < 16; ++k0)
    wf1[k0] = *(const bf16x8*)(w1 + (size_t)(jb + l15)*512 + k0*32 + l4*8);
  const unsigned short* w2 = wbf + ((size_t)(5*4 + d*2 + layer)) * 262144ull;
  bf16x8 wf2[16];
  #pragma unroll
  for (int k0 = 0; k0 < 16; ++k0)
    wf2[k0] = *(const bf16x8*)(w2 + (size_t)(jb + l15)*512 + k0*32 + l4*8);

  float* hb32d = hb32 + (size_t)d*2*32768;
  unsigned short* hb16d = hb16 + (size_t)d*2*32768;
  unsigned short* rhhd = rhhi + (size_t)d*32768;
  unsigned short* rhld = rhlo + (size_t)d*32768;
  int* fR = flags + d*64;
  int* fH = fR + 32;
  const unsigned short* xpz = xpzr + (size_t)(d*2 + 0)*SBH;
  const unsigned short* xpr = xpzr + (size_t)(d*2 + 1)*SBH;
  const float*          xpd = xph  + (size_t)d*SBH;

  const int myj = colg0 + (wv & 1)*16 + l15;   // elementwise column of this lane
  int budget = 1 << 21;
  __syncthreads();

  for (int t = 0; t < 512; ++t){
    if (!wait16(fH, t, tid, budget)) return;
    const unsigned short* hr16 = hb16d + (t & 1)*32768;
    const float*          hr32 = hb32d + (t & 1)*32768;
    const int idx = (layer == 0 && d == 1) ? (511 - t) : t;
    const size_t xbase = (size_t)idx * 32768;

    // ---- P1: z,r preacts.  A = h (bf16 mirror), B = Wh{z,r} rows ----
    f32x4 acc[4];
    #pragma unroll
    for (int m = 0; m < 4; ++m) acc[m] = (f32x4){0.f,0.f,0.f,0.f};
    #pragma unroll
    for (int k0 = 0; k0 < 16; ++k0){
      #pragma unroll
      for (int m = 0; m < 4; ++m){
        bf16x8 a = *(const bf16x8*)(hr16 + (size_t)(m*16 + l15)*512 + k0*32 + l4*8);
        acc[m] = __builtin_amdgcn_mfma_f32_16x16x32_bf16(a, wf1[k0], acc[m], 0,0,0);
      }
    }
    if (wv < 2){  // z
      #pragma unroll
      for (int m = 0; m < 4; ++m)
        #pragma unroll
        for (int i = 0; i < 4; ++i){
          int b = m*16 + l4*4 + i;
          float pre = acc[m][i] + b2f(xpz[xbase + (size_t)b*512 + myj]);
          zL[b][(wv & 1)*16 + l15] = 1.f/(1.f + __expf(-pre));
        }
    } else {      // r -> publish rh (hi/lo split)
      #pragma unroll
      for (int m = 0; m < 4; ++m)
        #pragma unroll
        for (int i = 0; i < 4; ++i){
          int b = m*16 + l4*4 + i;
          float pre = acc[m][i] + b2f(xpr[xbase + (size_t)b*512 + myj]);
          float r = 1.f/(1.f + __expf(-pre));
          float rhv = r * hr32[b*512 + myj];
          unsigned short hi = f2b(rhv);
          rhhd[b*512 + myj] = hi;
          rhld[b*512 + myj] = f2b(rhv - b2f(hi));
        }
    }
    __syncthreads();
    if (tid == 0){
      __threadfence();
      __hip_atomic_store(&fR[g], t + 1, __ATOMIC_RELEASE, __HIP_MEMORY_SCOPE_AGENT);
    }
    if (!wait16(fR, t + 1, tid, budget)) return;

    // ---- P2: h~ = tanh(xph + rh @ Whh^T), 3-term split MFMA ----
    f32x4 acc2[2];
    acc2[0] = (f32x4){0.f,0.f,0.f,0.f};
    acc2[1] = (f32x4){0.f,0.f,0.f,0.f};
    #pragma unroll
    for (int k0 = 0; k0 < 16; ++k0){
      bf16x8 wlo = *(const bf16x8*)&whhlo[((wv & 1)*16 + l15)*520 + k0*32 + l4*8];
      #pragma unroll
      for (int m = 0; m < 2; ++m){
        int mb = (wv >> 1)*2 + m;
        bf16x8 ahi = *(const bf16x8*)(rhhd + (size_t)(mb*16 + l15)*512 + k0*32 + l4*8);
        bf16x8 alo = *(const bf16x8*)(rhld + (size_t)(mb*16 + l15)*512 + k0*32 + l4*8);
        acc2[m] = __builtin_amdgcn_mfma_f32_16x16x32_bf16(ahi, wf2[k0], acc2[m], 0,0,0);
        acc2[m] = __builtin_amdgcn_mfma_f32_16x16x32_bf16(alo, wf2[k0], acc2[m], 0,0,0);
        acc2[m] = __builtin_amdgcn_mfma_f32_16x16x32_bf16(ahi, wlo,     acc2[m], 0,0,0);
      }
    }
    float* hw32 = hb32d + ((t + 1) & 1)*32768;
    unsigned short* hw16 = hb16d + ((t + 1) & 1)*32768;
    #pragma unroll
    for (int m = 0; m < 2; ++m){
      #pragma unroll
      for (int i = 0; i < 4; ++i){
        int b = ((wv >> 1)*2 + m)*16 + l4*4 + i;
        float pre = acc2[m][i] + xpd[xbase + (size_t)b*512 + myj];
        float e  = __expf(-2.f*fabsf(pre));
        float th = (1.f - e)/(1.f + e);
        th = (pre < 0.f) ? -th : th;
        float z    = zL[b][(wv & 1)*16 + l15];
        float hold = hr32[b*512 + myj];
        bool  msk  = (t < lenL[b]);
        float hn   = msk ? (hold + z*(th - hold)) : hold;
        hw32[b*512 + myj] = hn;
        hw16[b*512 + myj] = f2b(hn);
        if (layer == 0){
          h0buf[(size_t)d*SBH + ((size_t)t*64 + b)*512 + myj] = f2b(hn);
        } else {
          int sout = d ? (511 - t) : t;
          out[((size_t)b*512 + sout)*1024 + (size_t)d*512 + myj] = msk ? hn : 0.f;
        }
      }
    }
    __syncthreads();
    if (tid == 0){
      __threadfence();
      __hip_atomic_store(&fH[g], t + 1, __ATOMIC_RELEASE, __HIP_MEMORY_SCOPE_AGENT);
    }
  }
}

// ---------------- host launcher ----------------
extern "C" void kernel_launch(void* const* d_in, const int* in_sizes, int n_in,
                              void* d_out, int out_size, void* d_ws, size_t ws_size,
                              hipStream_t stream)
{
  const int*   tokens  = (const int*)  d_in[0];
  const int*   lengths = (const int*)  d_in[1];
  const float* table   = (const float*)d_in[2];
  const float* Wxz = (const float*)d_in[3];
  const float* bxz = (const float*)d_in[4];
  const float* Whz = (const float*)d_in[5];
  const float* Wxr = (const float*)d_in[6];
  const float* bxr = (const float*)d_in[7];
  const float* Whr = (const float*)d_in[8];
  const float* Wxh = (const float*)d_in[9];
  const float* bxh = (const float*)d_in[10];
  const float* Whh = (const float*)d_in[11];
  float* out = (float*)d_out;

  char* ws = (char*)d_ws;
  if (ws_size < WS_TOTAL){
    sentinel_kernel<<<1, 1, 0, stream>>>(out);
    return;
  }
  float*          hb32 = (float*)         (ws + OFF_HB32);
  unsigned short* hb16 = (unsigned short*)(ws + OFF_HB16);
  unsigned short* rhhi = (unsigned short*)(ws + OFF_RHHI);
  unsigned short* rhlo = (unsigned short*)(ws + OFF_RHLO);
  int*            flags= (int*)           (ws + OFF_FLAGS);
  unsigned short* xpzr = (unsigned short*)(ws + OFF_XPZR);
  float*          xph  = (float*)         (ws + OFF_XPH);
  unsigned short* h0   = (unsigned short*)(ws + OFF_H0);
  unsigned short* wbf  = (unsigned short*)(ws + OFF_WBF);

  hipMemsetAsync(ws, 0, CTRL_BYTES, stream);
  convert_kernel<<<dim3(1024, 6), 256, 0, stream>>>(Wxz, Wxr, Wxh, Whz, Whr, Whh, wbf);

  // layer 0
  xproj_kernel<<<dim3(256, 8, 6), 256, 0, stream>>>(0, tokens, table, h0, wbf,
                                                    bxz, bxr, bxh, xpzr, xph);
  recur_kernel<<<dim3(32), 256, 0, stream>>>(0, xpzr, xph, wbf, Whh, h0, out,
                                             lengths, hb32, hb16, rhhi, rhlo, flags);
  // layer 1
  hipMemsetAsync(ws, 0, CTRL_BYTES, stream);
  xproj_kernel<<<dim3(256, 8, 6), 256, 0, stream>>>(1, tokens, table, h0, wbf,
                                                    bxz, bxr, bxh, xpzr, xph);
  recur_kernel<<<dim3(32), 256, 0, stream>>>(1, xpzr, xph, wbf, Whh, h0, out,
                                             lengths, hb32, hb16, rhhi, rhlo, flags);
}